// Round 2
// baseline (139.068 us; speedup 1.0000x reference)
//
#include <hip/hip_runtime.h>

// DCN cross network, algebraically collapsed:
//   x_i = c_i * x0 + B_i,  B_i = prefix-sum of biases (row-independent)
//   c_{i+1} = c_i + (c_i * d_i + g_i),  d_i = dot(x0, w_i),  g_i = dot(B_i, w_i)
//   out = c_4 * x0 + Bsum
//
// v3: same 16-lanes-per-row / 4-rows-per-wave layout as v2, but the x HBM
// loads are issued FIRST (program-order before the preamble), so the
// per-wave preamble (28 L2 loads of w/b, Bsum prefix FMAs, three 6-step
// shuffle reductions) hides entirely under the x-load latency instead of
// delaying the HBM read phase by ~1 us per wave at kernel start.
// No barrier anywhere: a __syncthreads after the x-load issue would drain
// vmcnt(0) and serialize the overlap (guide §5: barrier drains all memory).
// Stores are nontemporal (out never re-read) to keep HBM write phase clean.

#define D 1024
#define NV4 (D / 4)      // 256 float4 per row
#define RPW 4            // rows per wave
#define LPR 16           // lanes per row
#define CPL (NV4 / LPR)  // 16 float4 chunks per lane

typedef float nfloat4 __attribute__((ext_vector_type(4)));  // native vec for NT store

__global__ __launch_bounds__(256, 4) void cross_v3_kernel(
    const float* __restrict__ x,
    const float* __restrict__ w,   // [4, 1024]
    const float* __restrict__ b,   // [4, 1024]
    float* __restrict__ out,
    int batch)
{
    __shared__ float4 ldsB[4][NV4];   // per-wave Bsum copy, 16 KiB/block

    const int tid  = (int)threadIdx.x;
    const int wvid = tid >> 6;
    const int lane = tid & 63;
    const int wid  = (int)blockIdx.x * 4 + wvid;
    const int row0 = wid * RPW;
    if (row0 >= batch) return;

    const int r = lane >> 4;                       // which of the wave's 4 rows
    const int t = lane & 15;                       // position within the row
    int rr = row0 + r;
    if (rr >= batch) rr = batch - 1;               // clamp (benign dup work)
    const int row = rr;

    // ---- FIRST: issue all x loads for the wave's 4 rows (16 float4/lane) ----
    // These are the HBM-bound stream; everything below hides under them.
    const float4* xr = (const float4*)x + (size_t)row * NV4;
    float4 xv[CPL];
#pragma unroll
    for (int c = 0; c < CPL; ++c) xv[c] = xr[c * LPR + t];

    const float4* w4 = (const float4*)w;
    const float4* b4 = (const float4*)b;

    // ---- preamble (overlapped with x latency): Bsum -> LDS, g1..g3 ----
    float g1 = 0.f, g2 = 0.f, g3 = 0.f;
#pragma unroll
    for (int c = 0; c < 4; ++c) {
        const int idx = c * 64 + lane;
        float4 bb0 = b4[idx], bb1 = b4[256 + idx];
        float4 bb2 = b4[512 + idx], bb3 = b4[768 + idx];
        float4 wv1 = w4[256 + idx], wv2 = w4[512 + idx], wv3 = w4[768 + idx];

        float4 B2, B3, Bs;
        B2.x = bb0.x + bb1.x; B2.y = bb0.y + bb1.y;
        B2.z = bb0.z + bb1.z; B2.w = bb0.w + bb1.w;
        B3.x = B2.x + bb2.x;  B3.y = B2.y + bb2.y;
        B3.z = B2.z + bb2.z;  B3.w = B2.w + bb2.w;
        Bs.x = B3.x + bb3.x;  Bs.y = B3.y + bb3.y;
        Bs.z = B3.z + bb3.z;  Bs.w = B3.w + bb3.w;
        ldsB[wvid][idx] = Bs;

        g1 = fmaf(bb0.x, wv1.x, g1); g1 = fmaf(bb0.y, wv1.y, g1);
        g1 = fmaf(bb0.z, wv1.z, g1); g1 = fmaf(bb0.w, wv1.w, g1);
        g2 = fmaf(B2.x,  wv2.x, g2); g2 = fmaf(B2.y,  wv2.y, g2);
        g2 = fmaf(B2.z,  wv2.z, g2); g2 = fmaf(B2.w,  wv2.w, g2);
        g3 = fmaf(B3.x,  wv3.x, g3); g3 = fmaf(B3.y,  wv3.y, g3);
        g3 = fmaf(B3.z,  wv3.z, g3); g3 = fmaf(B3.w,  wv3.w, g3);
    }

    // g-butterfly (full 64-lane reduce) — still under x-load latency
#pragma unroll
    for (int off = 32; off > 0; off >>= 1) {
        g1 += __shfl_xor(g1, off, 64);
        g2 += __shfl_xor(g2, off, 64);
        g3 += __shfl_xor(g3, off, 64);
    }

    // ---- 4 layer-dots over this lane's 64 elements of its row ----
    // w loads are L1/L2 hits; they interleave with the arriving x stream.
    float d0 = 0.f, d1 = 0.f, d2 = 0.f, d3 = 0.f;
#pragma unroll
    for (int c = 0; c < CPL; ++c) {
        const int wi = c * LPR + t;
        float4 wv0 = w4[wi];
        float4 wv1 = w4[256 + wi];
        float4 wv2 = w4[512 + wi];
        float4 wv3 = w4[768 + wi];
        float4 xc = xv[c];
        d0 = fmaf(xc.x, wv0.x, d0); d1 = fmaf(xc.x, wv1.x, d1);
        d2 = fmaf(xc.x, wv2.x, d2); d3 = fmaf(xc.x, wv3.x, d3);
        d0 = fmaf(xc.y, wv0.y, d0); d1 = fmaf(xc.y, wv1.y, d1);
        d2 = fmaf(xc.y, wv2.y, d2); d3 = fmaf(xc.y, wv3.y, d3);
        d0 = fmaf(xc.z, wv0.z, d0); d1 = fmaf(xc.z, wv1.z, d1);
        d2 = fmaf(xc.z, wv2.z, d2); d3 = fmaf(xc.z, wv3.z, d3);
        d0 = fmaf(xc.w, wv0.w, d0); d1 = fmaf(xc.w, wv1.w, d1);
        d2 = fmaf(xc.w, wv2.w, d2); d3 = fmaf(xc.w, wv3.w, d3);
    }

    // ---- ONE 4-step butterfly reduces all 4 rows at once (16-lane groups) ----
#pragma unroll
    for (int off = 8; off > 0; off >>= 1) {
        d0 += __shfl_xor(d0, off, 64);
        d1 += __shfl_xor(d1, off, 64);
        d2 += __shfl_xor(d2, off, 64);
        d3 += __shfl_xor(d3, off, 64);
    }

    const float c1 = 1.f + d0;
    const float c2 = c1 + fmaf(c1, d1, g1);
    const float c3 = c2 + fmaf(c2, d2, g2);
    const float c4 = c3 + fmaf(c3, d3, g3);

    // ---- epilogue: out = c4 * x0 + Bsum, nontemporal ----
    nfloat4* orow = (nfloat4*)out + (size_t)row * NV4;
#pragma unroll
    for (int c = 0; c < CPL; ++c) {
        const int wi = c * LPR + t;
        float4 Bs = ldsB[wvid][wi];
        nfloat4 o;
        o.x = fmaf(c4, xv[c].x, Bs.x);
        o.y = fmaf(c4, xv[c].y, Bs.y);
        o.z = fmaf(c4, xv[c].z, Bs.z);
        o.w = fmaf(c4, xv[c].w, Bs.w);
        __builtin_nontemporal_store(o, &orow[wi]);
    }
}

extern "C" void kernel_launch(void* const* d_in, const int* in_sizes, int n_in,
                              void* d_out, int out_size, void* d_ws, size_t ws_size,
                              hipStream_t stream) {
    const float* x = (const float*)d_in[0];
    const float* w = (const float*)d_in[1];
    const float* b = (const float*)d_in[2];
    float* out = (float*)d_out;

    const int batch = in_sizes[0] / D;              // 16384
    const int rows_per_block = RPW * (256 / 64);    // 16 rows per block
    const int grid = (batch + rows_per_block - 1) / rows_per_block;  // 1024
    cross_v3_kernel<<<grid, 256, 0, stream>>>(x, w, b, out, batch);
}

// Round 3
// 119.141 us; speedup vs baseline: 1.1673x; 1.1673x over previous
//
#include <hip/hip_runtime.h>

// DCN cross network, algebraically collapsed:
//   x_i = c_i * x0 + B_i,  B_i = prefix-sum of biases (row-independent)
//   c_{i+1} = c_i + (c_i * d_i + g_i),  d_i = dot(x0, w_i),  g_i = dot(B_i, w_i)
//   out = c_4 * x0 + Bsum
//
// v4: split into a tiny one-block PREP kernel (computes Bsum[1024] and
// g1..g3 once, into d_ws) and a preamble-free streaming MAIN kernel.
// Rationale (round-2 counters): main kernel was latency-bound (2.5 TB/s,
// VALUBusy 5%, VGPR=64 forced vmcnt waits into the preamble). Removing the
// per-wave preamble (28 L2 loads + 3 six-step butterflies, redundantly run
// by all 4096 waves at t=0) lets every wave start its HBM x-stream at
// cycle ~0. 2 rows/wave (32 lanes/row) keeps xv at 32 VGPRs, ~16 waves/CU,
// grid 2048 for block turnover. No LDS. NT stores keep out from evicting
// x in L3 (FETCH was 41.6 < 67 MB: L3 retention is real — preserve it).

#define D 1024
#define NV4 (D / 4)      // 256 float4 per row
#define RPW 2            // rows per wave
#define LPR 32           // lanes per row
#define CPL (NV4 / LPR)  // 8 float4 chunks per lane

typedef float nfloat4 __attribute__((ext_vector_type(4)));  // native vec for NT store

// ---------------- prep: Bsum -> ws[0..1023], g1..g3 -> ws[1024..1026] ----------------
__global__ void cross_prep_kernel(const float* __restrict__ w,
                                  const float* __restrict__ b,
                                  float* __restrict__ ws)
{
    __shared__ float red[3][4];
    const int t    = (int)threadIdx.x;   // 0..255, one float4 column each
    const int lane = t & 63;
    const int wv   = t >> 6;

    const float4* w4 = (const float4*)w;
    const float4* b4 = (const float4*)b;

    float4 bb0 = b4[t], bb1 = b4[256 + t], bb2 = b4[512 + t], bb3 = b4[768 + t];
    float4 wv1 = w4[256 + t], wv2 = w4[512 + t], wv3 = w4[768 + t];

    float4 B2, B3, Bs;
    B2.x = bb0.x + bb1.x; B2.y = bb0.y + bb1.y;
    B2.z = bb0.z + bb1.z; B2.w = bb0.w + bb1.w;
    B3.x = B2.x + bb2.x;  B3.y = B2.y + bb2.y;
    B3.z = B2.z + bb2.z;  B3.w = B2.w + bb2.w;
    Bs.x = B3.x + bb3.x;  Bs.y = B3.y + bb3.y;
    Bs.z = B3.z + bb3.z;  Bs.w = B3.w + bb3.w;
    ((float4*)ws)[t] = Bs;

    float g1 = 0.f, g2 = 0.f, g3 = 0.f;
    g1 = fmaf(bb0.x, wv1.x, g1); g1 = fmaf(bb0.y, wv1.y, g1);
    g1 = fmaf(bb0.z, wv1.z, g1); g1 = fmaf(bb0.w, wv1.w, g1);
    g2 = fmaf(B2.x,  wv2.x, g2); g2 = fmaf(B2.y,  wv2.y, g2);
    g2 = fmaf(B2.z,  wv2.z, g2); g2 = fmaf(B2.w,  wv2.w, g2);
    g3 = fmaf(B3.x,  wv3.x, g3); g3 = fmaf(B3.y,  wv3.y, g3);
    g3 = fmaf(B3.z,  wv3.z, g3); g3 = fmaf(B3.w,  wv3.w, g3);

#pragma unroll
    for (int off = 32; off > 0; off >>= 1) {
        g1 += __shfl_xor(g1, off, 64);
        g2 += __shfl_xor(g2, off, 64);
        g3 += __shfl_xor(g3, off, 64);
    }
    if (lane == 0) { red[0][wv] = g1; red[1][wv] = g2; red[2][wv] = g3; }
    __syncthreads();
    if (t == 0) {
        ws[1024] = red[0][0] + red[0][1] + red[0][2] + red[0][3];
        ws[1025] = red[1][0] + red[1][1] + red[1][2] + red[1][3];
        ws[1026] = red[2][0] + red[2][1] + red[2][2] + red[2][3];
    }
}

// ---------------- main: preamble-free streaming kernel ----------------
__global__ __launch_bounds__(256, 4) void cross_v4_kernel(
    const float* __restrict__ x,
    const float* __restrict__ w,    // [4, 1024]
    const float* __restrict__ ws,   // [1024] Bsum + [3] g
    float* __restrict__ out,
    int batch)
{
    const int tid  = (int)threadIdx.x;
    const int lane = tid & 63;
    const int wid  = (int)blockIdx.x * 4 + (tid >> 6);
    const int row0 = wid * RPW;
    if (row0 >= batch) return;

    const int r = lane >> 5;                 // which of the wave's 2 rows
    const int t = lane & 31;                 // position within the row
    int rr = row0 + r;
    if (rr >= batch) rr = batch - 1;         // clamp (benign dup work)
    const int row = rr;

    // ---- x loads first: the only HBM read stream, starts at cycle ~0 ----
    const float4* xr = (const float4*)x + (size_t)row * NV4;
    float4 xv[CPL];
#pragma unroll
    for (int c = 0; c < CPL; ++c) xv[c] = xr[c * LPR + t];

    // uniform g's (L2 hit, broadcast) — needed only after the butterfly
    const float g1 = ws[1024], g2 = ws[1025], g3 = ws[1026];

    // ---- 4 layer-dots over this lane's 32 elements of its row ----
    const float4* w4 = (const float4*)w;
    float d0 = 0.f, d1 = 0.f, d2 = 0.f, d3 = 0.f;
#pragma unroll
    for (int c = 0; c < CPL; ++c) {
        const int wi = c * LPR + t;
        float4 wv0 = w4[wi];
        float4 wv1 = w4[256 + wi];
        float4 wv2 = w4[512 + wi];
        float4 wv3 = w4[768 + wi];
        float4 xc = xv[c];
        d0 = fmaf(xc.x, wv0.x, d0); d1 = fmaf(xc.x, wv1.x, d1);
        d2 = fmaf(xc.x, wv2.x, d2); d3 = fmaf(xc.x, wv3.x, d3);
        d0 = fmaf(xc.y, wv0.y, d0); d1 = fmaf(xc.y, wv1.y, d1);
        d2 = fmaf(xc.y, wv2.y, d2); d3 = fmaf(xc.y, wv3.y, d3);
        d0 = fmaf(xc.z, wv0.z, d0); d1 = fmaf(xc.z, wv1.z, d1);
        d2 = fmaf(xc.z, wv2.z, d2); d3 = fmaf(xc.z, wv3.z, d3);
        d0 = fmaf(xc.w, wv0.w, d0); d1 = fmaf(xc.w, wv1.w, d1);
        d2 = fmaf(xc.w, wv2.w, d2); d3 = fmaf(xc.w, wv3.w, d3);
    }

    // ---- one 5-step butterfly reduces both rows at once (32-lane groups) ----
#pragma unroll
    for (int off = 16; off > 0; off >>= 1) {
        d0 += __shfl_xor(d0, off, 64);
        d1 += __shfl_xor(d1, off, 64);
        d2 += __shfl_xor(d2, off, 64);
        d3 += __shfl_xor(d3, off, 64);
    }

    const float c1 = 1.f + d0;
    const float c2 = c1 + fmaf(c1, d1, g1);
    const float c3 = c2 + fmaf(c2, d2, g2);
    const float c4 = c3 + fmaf(c3, d3, g3);

    // ---- epilogue: out = c4 * x0 + Bsum (Bsum from L2), nontemporal ----
    const float4* Bs4 = (const float4*)ws;
    nfloat4* orow = (nfloat4*)out + (size_t)row * NV4;
#pragma unroll
    for (int c = 0; c < CPL; ++c) {
        const int wi = c * LPR + t;
        float4 Bs = Bs4[wi];
        nfloat4 o;
        o.x = fmaf(c4, xv[c].x, Bs.x);
        o.y = fmaf(c4, xv[c].y, Bs.y);
        o.z = fmaf(c4, xv[c].z, Bs.z);
        o.w = fmaf(c4, xv[c].w, Bs.w);
        __builtin_nontemporal_store(o, &orow[wi]);
    }
}

extern "C" void kernel_launch(void* const* d_in, const int* in_sizes, int n_in,
                              void* d_out, int out_size, void* d_ws, size_t ws_size,
                              hipStream_t stream) {
    const float* x = (const float*)d_in[0];
    const float* w = (const float*)d_in[1];
    const float* b = (const float*)d_in[2];
    float* out = (float*)d_out;
    float* ws  = (float*)d_ws;

    const int batch = in_sizes[0] / D;              // 16384
    const int rows_per_block = RPW * (256 / 64);    // 8 rows per block
    const int grid = (batch + rows_per_block - 1) / rows_per_block;  // 2048

    cross_prep_kernel<<<1, 256, 0, stream>>>(w, b, ws);
    cross_v4_kernel<<<grid, 256, 0, stream>>>(x, w, ws, out, batch);
}